// Round 1
// baseline (151.660 us; speedup 1.0000x reference)
//
#include <hip/hip_runtime.h>
#include <hip/hip_bf16.h>

// Causal linear attention, chunked decomposition.
// B=4 H=16 T=2048 D=64. Chunk C=256, NC=8 chunks, BH=64 batch-heads.
// Kernel 1: per-(bh,chunk) KV state  KV_c = K_c^T V_c  (64x64 fp32) -> ws
// Kernel 2: per-(bh,chunk) output    O = Q_c * prefixKV + tril(Q_c K_c^T) V_c
// bf16 MFMA (16x16x32), fp32 accumulate. Threshold 36.96 >> bf16 error (~3).

#define B_   4
#define H_   16
#define T_   2048
#define D_   64
#define BH_  64
#define CCH  256
#define NCH  8
#define LPAD 8
#define LW   (D_ + LPAD)   // 72 bf16 = 144 B row stride (16B aligned)

typedef __bf16 bf16x8 __attribute__((ext_vector_type(8)));
typedef float  f32x4  __attribute__((ext_vector_type(4)));

// MFMA fragment layouts (16x16x32 bf16, HW-verified per guide):
//   A: A[m = lane&15][k = (lane>>4)*8 + j]   (8 contiguous k per lane)
//   B: B[k = (lane>>4)*8 + j][n = lane&15]
//   C/D: row = (lane>>4)*4 + reg, col = lane&15

__global__ __launch_bounds__(256) void kv_chunk_kernel(
    const float* __restrict__ k, const float* __restrict__ v,
    float* __restrict__ kvws) {
  __shared__ __align__(16) __bf16 KT[D_][LW];  // [d][s] transposed
  __shared__ __align__(16) __bf16 VT[D_][LW];  // [d][s] transposed

  const int tid  = threadIdx.x;
  const int lane = tid & 63;
  const int w    = tid >> 6;
  const int quad = lane >> 4;
  const int l15  = lane & 15;
  const int bh   = blockIdx.x >> 3;
  const int c    = blockIdx.x & (NCH - 1);
  const long base = ((long)bh * T_ + (long)c * CCH) * D_;

  const f32x4 vzero = {0.f, 0.f, 0.f, 0.f};
  f32x4 acc[4];
#pragma unroll
  for (int n = 0; n < 4; ++n) acc[n] = vzero;

  const int sl = tid >> 2;          // s within 64-tile
  const int d0 = (tid & 3) * 16;    // d start

  for (int st = 0; st < 4; ++st) {  // 4 s-tiles of 64 cover the 256 chunk
    __syncthreads();
    {
      const float* krow = k + base + (long)(st * 64 + sl) * D_ + d0;
      const float* vrow = v + base + (long)(st * 64 + sl) * D_ + d0;
#pragma unroll
      for (int x4 = 0; x4 < 4; ++x4) {
        float4 kx = *(const float4*)(krow + x4 * 4);
        float4 vx = *(const float4*)(vrow + x4 * 4);
        int dd = d0 + x4 * 4;
        KT[dd + 0][sl] = (__bf16)kx.x;
        KT[dd + 1][sl] = (__bf16)kx.y;
        KT[dd + 2][sl] = (__bf16)kx.z;
        KT[dd + 3][sl] = (__bf16)kx.w;
        VT[dd + 0][sl] = (__bf16)vx.x;
        VT[dd + 1][sl] = (__bf16)vx.y;
        VT[dd + 2][sl] = (__bf16)vx.z;
        VT[dd + 3][sl] = (__bf16)vx.w;
      }
    }
    __syncthreads();
    // KV[d1][d2] += sum_s K[s][d1]*V[s][d2]; A=K^T from KT, B=V from VT.
    // wave w owns d1 rows [16w,16w+16)
#pragma unroll
    for (int ks = 0; ks < 2; ++ks) {
      bf16x8 a = *(const bf16x8*)&KT[w * 16 + l15][ks * 32 + quad * 8];
#pragma unroll
      for (int n = 0; n < 4; ++n) {
        bf16x8 b = *(const bf16x8*)&VT[n * 16 + l15][ks * 32 + quad * 8];
        acc[n] = __builtin_amdgcn_mfma_f32_16x16x32_bf16(a, b, acc[n], 0, 0, 0);
      }
    }
  }
  float* out = kvws + ((long)blockIdx.x << 12);  // 64*64 fp32 per (bh,c)
#pragma unroll
  for (int n = 0; n < 4; ++n)
#pragma unroll
    for (int rr = 0; rr < 4; ++rr)
      out[(w * 16 + quad * 4 + rr) * 64 + n * 16 + l15] = acc[n][rr];
}

__global__ __launch_bounds__(256) void attn_chunk_kernel(
    const float* __restrict__ q, const float* __restrict__ k,
    const float* __restrict__ v, const float* __restrict__ kvws,
    float* __restrict__ out) {
  __shared__ __align__(16) __bf16 KVT[D_][LW];       // KVsum transposed [d2][d1]
  __shared__ __align__(16) __bf16 Kj[64][LW];        // key subtile row-major [s][d]
  __shared__ __align__(16) __bf16 VTj[D_][LW];       // value subtile transposed [d][s]
  __shared__ __align__(16) __bf16 Sw[4][16][LW];     // per-wave S tile [m][s]

  const int tid  = threadIdx.x;
  const int lane = tid & 63;
  const int w    = tid >> 6;
  const int quad = lane >> 4;
  const int l15  = lane & 15;
  const int bh   = blockIdx.x >> 3;
  const int c    = blockIdx.x & (NCH - 1);
  const long base = ((long)bh * T_ + (long)c * CCH) * D_;

  // ---- 1. prefix-sum KV states of prior chunks -> KVT (bf16, transposed)
  float kvacc[16];
#pragma unroll
  for (int i = 0; i < 16; ++i) kvacc[i] = 0.f;
  const float* wsbh = kvws + ((long)(bh * NCH) << 12);
  for (int cc = 0; cc < c; ++cc) {
    const float* p = wsbh + ((long)cc << 12) + tid;
#pragma unroll
    for (int i = 0; i < 16; ++i) kvacc[i] += p[i << 8];
  }
#pragma unroll
  for (int i = 0; i < 16; ++i) {
    int lin = tid + (i << 8);
    int d1 = lin >> 6, d2 = lin & 63;
    KVT[d2][d1] = (__bf16)kvacc[i];
  }

  // ---- 2. Q A-fragments in registers. wave w owns M-tiles {w, w+4, w+8, w+12}
  bf16x8 qf[4][2];
#pragma unroll
  for (int i = 0; i < 4; ++i) {
    int row = (w + 4 * i) * 16 + l15;
    const float* qp = q + base + (long)row * D_ + quad * 8;
#pragma unroll
    for (int ks = 0; ks < 2; ++ks) {
      float4 lo = *(const float4*)(qp + ks * 32);
      float4 hi = *(const float4*)(qp + ks * 32 + 4);
      bf16x8 f;
      f[0] = (__bf16)lo.x; f[1] = (__bf16)lo.y;
      f[2] = (__bf16)lo.z; f[3] = (__bf16)lo.w;
      f[4] = (__bf16)hi.x; f[5] = (__bf16)hi.y;
      f[6] = (__bf16)hi.z; f[7] = (__bf16)hi.w;
      qf[i][ks] = f;
    }
  }

  const f32x4 vzero = {0.f, 0.f, 0.f, 0.f};
  f32x4 acc[4][4];
#pragma unroll
  for (int i = 0; i < 4; ++i)
#pragma unroll
    for (int n = 0; n < 4; ++n) acc[i][n] = vzero;

  __syncthreads();  // KVT ready

  // ---- 3. inter-chunk: O += Q @ KVsum   (zeros when c==0; uniform work)
#pragma unroll
  for (int ks = 0; ks < 2; ++ks)
#pragma unroll
    for (int n = 0; n < 4; ++n) {
      bf16x8 b = *(const bf16x8*)&KVT[n * 16 + l15][ks * 32 + quad * 8];
#pragma unroll
      for (int i = 0; i < 4; ++i)
        acc[i][n] =
            __builtin_amdgcn_mfma_f32_16x16x32_bf16(qf[i][ks], b, acc[i][n], 0, 0, 0);
    }

  // ---- 4. intra-chunk causal part over 4 key subtiles of 64
  const int sl = tid >> 2;
  const int d0 = (tid & 3) * 16;
  for (int j = 0; j < 4; ++j) {
    __syncthreads();  // protect Kj/VTj reuse
    {
      const float* krow = k + base + (long)(j * 64 + sl) * D_ + d0;
      const float* vrow = v + base + (long)(j * 64 + sl) * D_ + d0;
#pragma unroll
      for (int x4 = 0; x4 < 4; ++x4) {
        float4 kx = *(const float4*)(krow + x4 * 4);
        float4 vx = *(const float4*)(vrow + x4 * 4);
        int dd = d0 + x4 * 4;
        Kj[sl][dd + 0] = (__bf16)kx.x;
        Kj[sl][dd + 1] = (__bf16)kx.y;
        Kj[sl][dd + 2] = (__bf16)kx.z;
        Kj[sl][dd + 3] = (__bf16)kx.w;
        VTj[dd + 0][sl] = (__bf16)vx.x;
        VTj[dd + 1][sl] = (__bf16)vx.y;
        VTj[dd + 2][sl] = (__bf16)vx.z;
        VTj[dd + 3][sl] = (__bf16)vx.w;
      }
    }
    __syncthreads();
    // M-tile (w+4i) needs key subtile j iff i >= j; i==j is the masked diagonal.
    for (int i = j; i < 4; ++i) {  // uniform trip count across waves
      f32x4 s[4];
#pragma unroll
      for (int n = 0; n < 4; ++n) s[n] = vzero;
#pragma unroll
      for (int ks = 0; ks < 2; ++ks) {
#pragma unroll
        for (int n = 0; n < 4; ++n) {
          bf16x8 b = *(const bf16x8*)&Kj[n * 16 + l15][ks * 32 + quad * 8];
          s[n] = __builtin_amdgcn_mfma_f32_16x16x32_bf16(qf[i][ks], b, s[n], 0, 0, 0);
        }
      }
      __syncthreads();  // prior Sw reads done before overwrite
#pragma unroll
      for (int n = 0; n < 4; ++n) {
#pragma unroll
        for (int rr = 0; rr < 4; ++rr) {
          float val = s[n][rr];
          if (i == j) {
            // keep iff key_local <= query_local within the 64-aligned block
            if (n * 16 + l15 > 16 * w + quad * 4 + rr) val = 0.f;
          }
          Sw[w][quad * 4 + rr][n * 16 + l15] = (__bf16)val;
        }
      }
      __syncthreads();  // Sw written before reads
#pragma unroll
      for (int ks = 0; ks < 2; ++ks) {
        bf16x8 a = *(const bf16x8*)&Sw[w][l15][ks * 32 + quad * 8];
#pragma unroll
        for (int n = 0; n < 4; ++n) {
          bf16x8 b = *(const bf16x8*)&VTj[n * 16 + l15][ks * 32 + quad * 8];
          acc[i][n] =
              __builtin_amdgcn_mfma_f32_16x16x32_bf16(a, b, acc[i][n], 0, 0, 0);
        }
      }
    }
  }

  // ---- 5. epilogue: write O (fp32)
  float* op = out + base;
#pragma unroll
  for (int i = 0; i < 4; ++i) {
    int row = (w + 4 * i) * 16 + quad * 4;
#pragma unroll
    for (int n = 0; n < 4; ++n)
#pragma unroll
      for (int rr = 0; rr < 4; ++rr)
        op[(long)(row + rr) * D_ + n * 16 + l15] = acc[i][n][rr];
  }
}

extern "C" void kernel_launch(void* const* d_in, const int* in_sizes, int n_in,
                              void* d_out, int out_size, void* d_ws, size_t ws_size,
                              hipStream_t stream) {
  const float* q = (const float*)d_in[0];
  const float* k = (const float*)d_in[1];
  const float* v = (const float*)d_in[2];
  float* out = (float*)d_out;
  float* kvws = (float*)d_ws;  // needs BH_*NCH*64*64*4 = 8 MiB

  hipLaunchKernelGGL(kv_chunk_kernel, dim3(BH_ * NCH), dim3(256), 0, stream,
                     k, v, kvws);
  hipLaunchKernelGGL(attn_chunk_kernel, dim3(BH_ * NCH), dim3(256), 0, stream,
                     q, k, v, kvws, out);
}